// Round 10
// baseline (249.650 us; speedup 1.0000x reference)
//
#include <hip/hip_runtime.h>
#include <math.h>

#define LAG 168
#define HOR 24
#define DM 6
#define FFD 18
#define NL 3
#define WPB 2          // independent waves (samples) per workgroup
#define LNEPS 1e-5f

typedef unsigned int u32;
typedef float f32x4 __attribute__((ext_vector_type(4)));
typedef float f32x16 __attribute__((ext_vector_type(16)));
typedef short s16x8 __attribute__((ext_vector_type(8)));
typedef __bf16 bfx2 __attribute__((ext_vector_type(2)));

// Per-wave LDS slice (4-byte words). One wave per slice -> in-order LDS pipe,
// no barriers; overlays are same-wave-safe (r6-proven).
//   [0..799]    V^T bf16 [8][200], pitch 100 words; row6 = ones (denominator,
//               re-init each layer). Read once per layer into vf regs, then
//               dead -> O-stage bf16 [192][8] (768 words) overlays [0..767].
//   [800..1375] P-pack bf16 [32 q][36], pitch 18 words.
//   [0..1599]   (after all layers) head scratch fp32 [64][25].
#define PP    800
#define SLICE 1600     // 6400 B/wave; block = 12800 B -> 12 blocks/CU = 24 waves

__device__ __forceinline__ u32 pkbf(float a, float b) {
    bfx2 t; t[0] = (__bf16)a; t[1] = (__bf16)b;
    return __builtin_bit_cast(u32, t);
}
__device__ __forceinline__ s16x8 mk8(u32 a, u32 b, u32 c, u32 d) {
    uint4 u; u.x = a; u.y = b; u.z = c; u.w = d;
    return __builtin_bit_cast(s16x8, u);
}
__device__ __forceinline__ float b2f(unsigned short h) {
    u32 u = ((u32)h) << 16; return __builtin_bit_cast(float, u);
}
__device__ __forceinline__ void ln6(const float* r, const float* g, const float* bb, float* outv) {
    float m = (r[0]+r[1]+r[2]+r[3]+r[4]+r[5]) * (1.0f/6.0f);
    float v = 0.f;
#pragma unroll
    for (int d = 0; d < DM; ++d) { float t = r[d]-m; v += t*t; }
    v *= (1.0f/6.0f);
    float rs = __builtin_amdgcn_rsqf(v + LNEPS);
#pragma unroll
    for (int d = 0; d < DM; ++d) outv[d] = (r[d]-m)*rs*g[d] + bb[d];
}

// min-waves 4 -> VGPR cap 128 (same effective cap as the proven r3 build,
// which compiled to 64 VGPR). Caps tighter than natural need spill to
// scratch (R4/R5: FETCH 742/567 MB, 2x slower) -- do not lower.
__global__ __launch_bounds__(64*WPB, 4) void tfenc_kernel(
    const float* __restrict__ input, const float* __restrict__ pos_emb,
    const float* __restrict__ ipw, const float* __restrict__ ipb,
    const float* __restrict__ ow,  const float* __restrict__ obp,
    const float* __restrict__ l1g, const float* __restrict__ l1b,
    const float* __restrict__ f1w, const float* __restrict__ f1b,
    const float* __restrict__ f2w, const float* __restrict__ f2b,
    const float* __restrict__ l2g, const float* __restrict__ l2b,
    const float* __restrict__ hw,  const float* __restrict__ hb,
    float* __restrict__ out)
{
    __shared__ __align__(16) float lds[WPB * SLICE];

    const int L   = threadIdx.x & 63;
    const int wid = threadIdx.x >> 6;
    const int b   = blockIdx.x * WPB + wid;   // sample index

    float*  sl  = lds + wid * SLICE;
    __bf16* slh = (__bf16*)sl;
    u32*    slu = (u32*)sl;

    float hv[3][DM], xv[3][DM];
#pragma unroll
    for (int i = 0; i < 3; ++i) {
        int r = L + 64*i;
        bool real = (r < LAG);
        xv[i][0] = real ? input[(size_t)b*LAG + r] : 0.f;
#pragma unroll
        for (int j = 0; j < 5; ++j)
            xv[i][1+j] = real ? pos_emb[r*5 + j] : 0.f;
#pragma unroll
        for (int d = 0; d < DM; ++d) hv[i][d] = xv[i][d];
    }

    const float cQ = 0.5889116917845058f;  // log2(e)/sqrt(6)
    const u32 himask = (L & 32) ? 0u : ~0u;
    const int permA = 4*(L & 31);
    const int permB = permA + 128;

#pragma unroll 1
    for (int il = 0; il < NL; ++il) {
        const float* Wip = ipw + il*3*DM*DM;
        const float* bip = ipb + il*3*DM;
        const float* Wo  = ow  + il*DM*DM;
        const float* bo  = obp + il*DM;
        const float* g1  = l1g + il*DM;     const float* c1  = l1b + il*DM;
        const float* W1  = f1w + il*FFD*DM; const float* bb1 = f1b + il*FFD;
        const float* W2  = f2w + il*DM*FFD; const float* bb2 = f2b + il*DM;
        const float* g2  = l2g + il*DM;     const float* c2  = l2b + il*DM;

        // ---- QKV projection; stage V^T to LDS; pack q*cQ, k to bf16 dwords ----
        u32 qp[3][3], kp[3][3];
#pragma unroll
        for (int i = 0; i < 3; ++i) {
            int r = L + 64*i;
            float qv[6], kv[6], vv[6];
#pragma unroll
            for (int e = 0; e < 18; ++e) {
                float a = bip[e];
#pragma unroll
                for (int d = 0; d < DM; ++d) a += hv[i][d]*Wip[e*DM+d];
                if (e < 6) qv[e] = a*cQ;
                else if (e < 12) kv[e-6] = a;
                else vv[e-12] = a;
            }
            qp[i][0]=pkbf(qv[0],qv[1]); qp[i][1]=pkbf(qv[2],qv[3]); qp[i][2]=pkbf(qv[4],qv[5]);
            kp[i][0]=pkbf(kv[0],kv[1]); kp[i][1]=pkbf(kv[2],kv[3]); kp[i][2]=pkbf(kv[4],kv[5]);
#pragma unroll
            for (int d = 0; d < DM; ++d)
                slh[d*200 + r] = (__bf16)vv[d];
        }
        // ones row = softmax denominator column (V^T row 6), re-init per layer
        // (the O-stage overlay clobbers it each layer)
        {
            __bf16 one = (__bf16)1.0f;
            slh[6*200 + L] = one;
            slh[6*200 + 64 + L] = one;
            slh[6*200 + 128 + L] = one;
        }

        // ---- K fragments (A of 32x32x16) via bpermute ----
        s16x8 kf[6];
#pragma unroll
        for (int kt = 0; kt < 6; ++kt) {
            int adr = (kt & 1) ? permB : permA;
            int slo = kt >> 1;
            u32 w0 = ((u32)__builtin_amdgcn_ds_bpermute(adr, (int)kp[slo][0])) & himask;
            u32 w1 = ((u32)__builtin_amdgcn_ds_bpermute(adr, (int)kp[slo][1])) & himask;
            u32 w2 = ((u32)__builtin_amdgcn_ds_bpermute(adr, (int)kp[slo][2])) & himask;
            kf[kt] = mk8(w0, w1, w2, 0u);
        }
        // ---- V fragments (B of 16x16x32), register-cached for the layer ----
        // (d >= 7 lanes read the ones row: their output cols are discarded)
        s16x8 vf[6];
        {
            int d = L & 15;
            int vrow = d < 7 ? d : 6;
            const u32* vb = slu + (vrow*100 + (L >> 4)*4);
#pragma unroll
            for (int kc = 0; kc < 6; ++kc)
                vf[kc] = __builtin_bit_cast(s16x8, *(const uint4*)(vb + kc*16));
        }

        const int wrbase = PP + (L & 31)*18 + 2*(L >> 5);
        const int rdbase = PP + (L & 15)*18 + 4*(L >> 4);

        // ---- attention: S^T = K*Q^T (32x32), exp2, LDS repack, P*V (16x16) ----
#pragma unroll
        for (int qt = 0; qt < 6; ++qt) {
            int adr = (qt & 1) ? permB : permA;
            int slo = qt >> 1;
            u32 u0 = ((u32)__builtin_amdgcn_ds_bpermute(adr, (int)qp[slo][0])) & himask;
            u32 u1 = ((u32)__builtin_amdgcn_ds_bpermute(adr, (int)qp[slo][1])) & himask;
            u32 u2 = ((u32)__builtin_amdgcn_ds_bpermute(adr, (int)qp[slo][2])) & himask;
            s16x8 qf = mk8(u0, u1, u2, 0u);
            f32x4 acc0 = {0.f,0.f,0.f,0.f};
            f32x4 acc1 = {0.f,0.f,0.f,0.f};
#pragma unroll
            for (int kt = 0; kt < 6; ++kt) {
                const f32x16 z = {};
                f32x16 S = __builtin_amdgcn_mfma_f32_32x32x16_bf16(kf[kt], qf, z, 0, 0, 0);
                u32 w[8];
#pragma unroll
                for (int jj = 0; jj < 8; ++jj) {
                    if (kt == 5 && jj >= 2) w[jj] = 0u;   // keys >= 168 masked
                    else w[jj] = pkbf(__builtin_amdgcn_exp2f(S[2*jj]),
                                      __builtin_amdgcn_exp2f(S[2*jj+1]));
                }
                u32* ppw = slu + wrbase;
                { uint2 t; t.x=w[0]; t.y=w[1]; *(uint2*)(ppw     ) = t; }
                { uint2 t; t.x=w[2]; t.y=w[3]; *(uint2*)(ppw +  4) = t; }
                { uint2 t; t.x=w[4]; t.y=w[5]; *(uint2*)(ppw +  8) = t; }
                { uint2 t; t.x=w[6]; t.y=w[7]; *(uint2*)(ppw + 12) = t; }
                const u32* rr = slu + rdbase;
                uint2 a00 = *(const uint2*)(rr);
                uint2 a01 = *(const uint2*)(rr + 2);
                uint2 a10 = *(const uint2*)(rr + 288);
                uint2 a11 = *(const uint2*)(rr + 290);
                acc0 = __builtin_amdgcn_mfma_f32_16x16x32_bf16(mk8(a00.x,a00.y,a01.x,a01.y), vf[kt], acc0, 0,0,0);
                acc1 = __builtin_amdgcn_mfma_f32_16x16x32_bf16(mk8(a10.x,a10.y,a11.x,a11.y), vf[kt], acc1, 0,0,0);
            }
            // stage O tiles to bf16 over the dead V^T region (vf cached)
            int d = L & 15;
            if (d < 7) {
                int qb = 32*qt + 4*(L >> 4);
#pragma unroll
                for (int r2 = 0; r2 < 4; ++r2) {
                    slh[(qb + r2)*8 + d]      = (__bf16)acc0[r2];
                    slh[(qb + 16 + r2)*8 + d] = (__bf16)acc1[r2];
                }
            }
        }

        // ---- epilogue per owned row: normalize, out-proj, LN, FF, LN ----
#pragma unroll
        for (int i = 0; i < 3; ++i) {
            int r = L + 64*i;
            s16x8 ov = __builtin_bit_cast(s16x8, *(const uint4*)(slh + r*8));
            float o[7];
#pragma unroll
            for (int d = 0; d < 7; ++d) o[d] = b2f((unsigned short)ov[d]);
            float inv = __builtin_amdgcn_rcpf(o[6]);
            float att[6], rv[6];
#pragma unroll
            for (int d = 0; d < 6; ++d) att[d] = o[d]*inv;
#pragma unroll
            for (int e = 0; e < 6; ++e) {
                float a = bo[e];
#pragma unroll
                for (int d = 0; d < 6; ++d) a += att[d]*Wo[e*6+d];
                rv[e] = hv[i][e] + a;
            }
            ln6(rv, g1, c1, hv[i]);
            float o2[6];
#pragma unroll
            for (int d = 0; d < 6; ++d) o2[d] = bb2[d];
#pragma unroll
            for (int ff = 0; ff < FFD; ++ff) {
                float a = bb1[ff];
#pragma unroll
                for (int d = 0; d < 6; ++d) a += hv[i][d]*W1[ff*6+d];
                a = fmaxf(a, 0.f);
#pragma unroll
                for (int d = 0; d < 6; ++d) o2[d] += a*W2[d*FFD+ff];
            }
#pragma unroll
            for (int d = 0; d < 6; ++d) rv[d] = hv[i][d] + o2[d];
            ln6(rv, g2, c2, hv[i]);
        }
    }

    // ---- final residual+relu (registers), head GEMV (r3-verbatim) ----
    float hf[3][6];
#pragma unroll
    for (int i = 0; i < 3; ++i) {
        int r = L + 64*i;
        bool real = (r < LAG);
#pragma unroll
        for (int d = 0; d < 6; ++d)
            hf[i][d] = real ? fmaxf(hv[i][d] + xv[i][d], 0.f) : 0.f;
    }
    float pt[24];
#pragma unroll
    for (int t = 0; t < 24; ++t) pt[t] = 0.f;
#pragma unroll
    for (int i = 0; i < 3; ++i) {
        int r = L + 64*i;
        if (r < LAG) {
            const float* wr = hw + r*6;
#pragma unroll
            for (int t = 0; t < 24; ++t) {
                const float2* wp = (const float2*)(wr + t*1008);
                float2 w0 = wp[0], w1 = wp[1], w2 = wp[2];
                pt[t] += w0.x*hf[i][0] + w0.y*hf[i][1] + w1.x*hf[i][2]
                       + w1.y*hf[i][3] + w2.x*hf[i][4] + w2.y*hf[i][5];
            }
        }
    }
#pragma unroll
    for (int t = 0; t < 24; ++t) sl[L*25 + t] = pt[t];
    if (L < HOR) {
        float s = hb[L];
#pragma unroll 8
        for (int j = 0; j < 64; ++j) s += sl[j*25 + L];
        out[(size_t)b*HOR + L] = s;
    }
}

extern "C" void kernel_launch(void* const* d_in, const int* in_sizes, int n_in,
                              void* d_out, int out_size, void* d_ws, size_t ws_size,
                              hipStream_t stream) {
    const float* input   = (const float*)d_in[0];
    const float* pos_emb = (const float*)d_in[1];
    const float* ipw     = (const float*)d_in[2];
    const float* ipb     = (const float*)d_in[3];
    const float* ow      = (const float*)d_in[4];
    const float* ob      = (const float*)d_in[5];
    const float* l1g     = (const float*)d_in[6];
    const float* l1b     = (const float*)d_in[7];
    const float* f1w     = (const float*)d_in[8];
    const float* f1b     = (const float*)d_in[9];
    const float* f2w     = (const float*)d_in[10];
    const float* f2b     = (const float*)d_in[11];
    const float* l2g     = (const float*)d_in[12];
    const float* l2b     = (const float*)d_in[13];
    const float* hw      = (const float*)d_in[14];
    const float* hb      = (const float*)d_in[15];
    float* out = (float*)d_out;

    const int B = in_sizes[0] / LAG;
    tfenc_kernel<<<dim3(B / WPB), dim3(64 * WPB), 0, stream>>>(
        input, pos_emb, ipw, ipb, ow, ob, l1g, l1b,
        f1w, f1b, f2w, f2b, l2g, l2b, hw, hb, out);
}

// Round 11
// 180.435 us; speedup vs baseline: 1.3836x; 1.3836x over previous
//
#include <hip/hip_runtime.h>
#include <math.h>

#define LAG 168
#define HOR 24
#define DM 6
#define FFD 18
#define NL 3
#define LNEPS 1e-5f

typedef unsigned int u32;
typedef float f32x2 __attribute__((ext_vector_type(2)));
typedef float f32x4 __attribute__((ext_vector_type(4)));
typedef float f32x16 __attribute__((ext_vector_type(16)));
typedef short s16x8 __attribute__((ext_vector_type(8)));
typedef __bf16 bfx2 __attribute__((ext_vector_type(2)));

// LDS layout (4-byte words) -- single wave per block (r3-proven structure):
//   [0..799]    V^T bf16 [8][200] pitch 100 words; row6=ones, row7=pad
//   [800..1375] P-pack bf16 [32 q][36], pitch 18 words
//   word 1376.. O-stage bf16 [192][8]  (half-index base OOH)
//   [0..1599]   (overlay, after layers) head scratch fp32 [64][25]
#define PP    800
#define OOH   2752
#define HEADS 0
#define LDSW  2144     // 8576 B -> proven 40% occupancy, VGPR 64

__device__ __forceinline__ u32 pkbf(float a, float b) {
    bfx2 t; t[0] = (__bf16)a; t[1] = (__bf16)b;
    return __builtin_bit_cast(u32, t);
}
__device__ __forceinline__ s16x8 mk8(u32 a, u32 b, u32 c, u32 d) {
    uint4 u; u.x = a; u.y = b; u.z = c; u.w = d;
    return __builtin_bit_cast(s16x8, u);
}
__device__ __forceinline__ float b2f(unsigned short h) {
    u32 u = ((u32)h) << 16; return __builtin_bit_cast(float, u);
}
// packed fp32 fma: maps to v_pk_fma_f32 (2 independent FMAs / instr)
__device__ __forceinline__ f32x2 pkfma(f32x2 a, f32x2 b, f32x2 c) {
    return __builtin_elementwise_fma(a, b, c);
}
__device__ __forceinline__ void ln6(const float* r, const float* g, const float* bb, float* outv) {
    float m = (r[0]+r[1]+r[2]+r[3]+r[4]+r[5]) * (1.0f/6.0f);
    float v = 0.f;
#pragma unroll
    for (int d = 0; d < DM; ++d) { float t = r[d]-m; v += t*t; }
    v *= (1.0f/6.0f);
    float rs = __builtin_amdgcn_rsqf(v + LNEPS);
#pragma unroll
    for (int d = 0; d < DM; ++d) outv[d] = (r[d]-m)*rs*g[d] + bb[d];
}

__global__ __launch_bounds__(64, 4) void tfenc_kernel(
    const float* __restrict__ input, const float* __restrict__ pos_emb,
    const float* __restrict__ ipw, const float* __restrict__ ipb,
    const float* __restrict__ ow,  const float* __restrict__ obp,
    const float* __restrict__ l1g, const float* __restrict__ l1b,
    const float* __restrict__ f1w, const float* __restrict__ f1b,
    const float* __restrict__ f2w, const float* __restrict__ f2b,
    const float* __restrict__ l2g, const float* __restrict__ l2b,
    const float* __restrict__ hw,  const float* __restrict__ hb,
    float* __restrict__ out)
{
    __shared__ __align__(16) float lds[LDSW];
    __bf16* ldsh = (__bf16*)lds;
    u32*    ldsu = (u32*)lds;

    const int L = threadIdx.x;
    const int b = blockIdx.x;

    // persistent Vt rows: row 7 = zeros (pad d), row 6 = ones (denominator)
    lds[700 + L] = 0.f;
    if (L < 36) lds[700 + 64 + L] = 0.f;
    {
        __bf16 one = (__bf16)1.0f;
        ldsh[6*200 + L] = one;
        ldsh[6*200 + 64 + L] = one;
        ldsh[6*200 + 128 + L] = one;
    }

    float hv[3][DM], xv[3][DM];
#pragma unroll
    for (int i = 0; i < 3; ++i) {
        int r = L + 64*i;
        bool real = (r < LAG);
        xv[i][0] = real ? input[(size_t)b*LAG + r] : 0.f;
#pragma unroll
        for (int j = 0; j < 5; ++j)
            xv[i][1+j] = real ? pos_emb[r*5 + j] : 0.f;
#pragma unroll
        for (int d = 0; d < DM; ++d) hv[i][d] = xv[i][d];
    }

    const float cQ = 0.5889116917845058f;  // log2(e)/sqrt(6)
    const u32 himask = (L & 32) ? 0u : ~0u;
    const int permA = 4*(L & 31);
    const int permB = permA + 128;

#pragma unroll 1
    for (int il = 0; il < NL; ++il) {
        const float* Wip = ipw + il*3*DM*DM;
        const float* bip = ipb + il*3*DM;
        const float* Wo  = ow  + il*DM*DM;
        const float* bo  = obp + il*DM;
        const float* g1  = l1g + il*DM;     const float* c1  = l1b + il*DM;
        const float* W1  = f1w + il*FFD*DM; const float* bb1 = f1b + il*FFD;
        const float* W2  = f2w + il*DM*FFD; const float* bb2 = f2b + il*DM;
        const float* g2  = l2g + il*DM;     const float* c2  = l2b + il*DM;

        // ---- QKV projection (packed-f32 dot products); stage V^T ----
        u32 qp[3][3], kp[3][3];
#pragma unroll
        for (int i = 0; i < 3; ++i) {
            int r = L + 64*i;
            f32x2 h2[3];
            h2[0].x = hv[i][0]; h2[0].y = hv[i][1];
            h2[1].x = hv[i][2]; h2[1].y = hv[i][3];
            h2[2].x = hv[i][4]; h2[2].y = hv[i][5];
            float qv[6], kv[6], vv[6];
#pragma unroll
            for (int e = 0; e < 18; ++e) {
                const float* wr = Wip + e*6;
                f32x2 w0; w0.x = wr[0]; w0.y = wr[1];
                f32x2 w1; w1.x = wr[2]; w1.y = wr[3];
                f32x2 w2; w2.x = wr[4]; w2.y = wr[5];
                f32x2 acc; acc.x = bip[e]; acc.y = 0.f;
                acc = pkfma(h2[0], w0, acc);
                acc = pkfma(h2[1], w1, acc);
                acc = pkfma(h2[2], w2, acc);
                float a = acc.x + acc.y;
                if (e < 6) qv[e] = a*cQ;
                else if (e < 12) kv[e-6] = a;
                else vv[e-12] = a;
            }
            qp[i][0]=pkbf(qv[0],qv[1]); qp[i][1]=pkbf(qv[2],qv[3]); qp[i][2]=pkbf(qv[4],qv[5]);
            kp[i][0]=pkbf(kv[0],kv[1]); kp[i][1]=pkbf(kv[2],kv[3]); kp[i][2]=pkbf(kv[4],kv[5]);
#pragma unroll
            for (int d = 0; d < DM; ++d)
                ldsh[d*200 + r] = (__bf16)vv[d];
        }

        // ---- K fragments (A of 32x32x16) via bpermute ----
        s16x8 kf[6];
#pragma unroll
        for (int kt = 0; kt < 6; ++kt) {
            int adr = (kt & 1) ? permB : permA;
            int slo = kt >> 1;
            u32 w0 = ((u32)__builtin_amdgcn_ds_bpermute(adr, (int)kp[slo][0])) & himask;
            u32 w1 = ((u32)__builtin_amdgcn_ds_bpermute(adr, (int)kp[slo][1])) & himask;
            u32 w2 = ((u32)__builtin_amdgcn_ds_bpermute(adr, (int)kp[slo][2])) & himask;
            kf[kt] = mk8(w0, w1, w2, 0u);
        }
        // ---- V fragments (B of 16x16x32), register-cached for the layer ----
        s16x8 vf[6];
        {
            int d = L & 15;
            int vrow = d < 7 ? d : 7;
            const u32* vb = ldsu + (vrow*100 + (L >> 4)*4);
#pragma unroll
            for (int kc = 0; kc < 6; ++kc)
                vf[kc] = __builtin_bit_cast(s16x8, *(const uint4*)(vb + kc*16));
        }

        const int wrbase = PP + (L & 31)*18 + 2*(L >> 5);
        const int rdbase = PP + (L & 15)*18 + 4*(L >> 4);

        // ---- attention: S^T = K*Q^T (32x32), exp2, LDS repack, P*V (16x16) ----
#pragma unroll
        for (int qt = 0; qt < 6; ++qt) {
            int adr = (qt & 1) ? permB : permA;
            int slo = qt >> 1;
            u32 u0 = ((u32)__builtin_amdgcn_ds_bpermute(adr, (int)qp[slo][0])) & himask;
            u32 u1 = ((u32)__builtin_amdgcn_ds_bpermute(adr, (int)qp[slo][1])) & himask;
            u32 u2 = ((u32)__builtin_amdgcn_ds_bpermute(adr, (int)qp[slo][2])) & himask;
            s16x8 qf = mk8(u0, u1, u2, 0u);
            f32x4 acc0 = {0.f,0.f,0.f,0.f};
            f32x4 acc1 = {0.f,0.f,0.f,0.f};
#pragma unroll
            for (int kt = 0; kt < 6; ++kt) {
                const f32x16 z = {};
                f32x16 S = __builtin_amdgcn_mfma_f32_32x32x16_bf16(kf[kt], qf, z, 0, 0, 0);
                u32 w[8];
#pragma unroll
                for (int jj = 0; jj < 8; ++jj) {
                    if (kt == 5 && jj >= 2) w[jj] = 0u;   // keys >= 168 masked
                    else w[jj] = pkbf(__builtin_amdgcn_exp2f(S[2*jj]),
                                      __builtin_amdgcn_exp2f(S[2*jj+1]));
                }
                u32* ppw = ldsu + wrbase;
                { uint2 t; t.x=w[0]; t.y=w[1]; *(uint2*)(ppw     ) = t; }
                { uint2 t; t.x=w[2]; t.y=w[3]; *(uint2*)(ppw +  4) = t; }
                { uint2 t; t.x=w[4]; t.y=w[5]; *(uint2*)(ppw +  8) = t; }
                { uint2 t; t.x=w[6]; t.y=w[7]; *(uint2*)(ppw + 12) = t; }
                const u32* rr = ldsu + rdbase;
                uint2 a00 = *(const uint2*)(rr);
                uint2 a01 = *(const uint2*)(rr + 2);
                uint2 a10 = *(const uint2*)(rr + 288);
                uint2 a11 = *(const uint2*)(rr + 290);
                acc0 = __builtin_amdgcn_mfma_f32_16x16x32_bf16(mk8(a00.x,a00.y,a01.x,a01.y), vf[kt], acc0, 0,0,0);
                acc1 = __builtin_amdgcn_mfma_f32_16x16x32_bf16(mk8(a10.x,a10.y,a11.x,a11.y), vf[kt], acc1, 0,0,0);
            }
            // stage O tiles to bf16 (col d = L&15 < 7 useful; col 6 = denom)
            int d = L & 15;
            if (d < 7) {
                int qb = 32*qt + 4*(L >> 4);
                __bf16* ob16 = ldsh + OOH;
#pragma unroll
                for (int r2 = 0; r2 < 4; ++r2) {
                    ob16[(qb + r2)*8 + d]      = (__bf16)acc0[r2];
                    ob16[(qb + 16 + r2)*8 + d] = (__bf16)acc1[r2];
                }
            }
        }

        // ---- epilogue per owned row (packed-f32 row math) ----
#pragma unroll
        for (int i = 0; i < 3; ++i) {
            int r = L + 64*i;
            s16x8 ov = __builtin_bit_cast(s16x8, *(const uint4*)(ldsh + OOH + r*8));
            float inv = __builtin_amdgcn_rcpf(b2f((unsigned short)ov[6]));
            f32x2 iv; iv.x = inv; iv.y = inv;
            f32x2 att2[3];
#pragma unroll
            for (int j = 0; j < 3; ++j) {
                f32x2 op; op.x = b2f((unsigned short)ov[2*j]);
                op.y = b2f((unsigned short)ov[2*j+1]);
                att2[j] = op * iv;
            }
            float rv[6];
#pragma unroll
            for (int e = 0; e < 6; ++e) {
                const float* wr = Wo + e*6;
                f32x2 w0; w0.x = wr[0]; w0.y = wr[1];
                f32x2 w1; w1.x = wr[2]; w1.y = wr[3];
                f32x2 w2; w2.x = wr[4]; w2.y = wr[5];
                f32x2 acc; acc.x = bo[e]; acc.y = 0.f;
                acc = pkfma(att2[0], w0, acc);
                acc = pkfma(att2[1], w1, acc);
                acc = pkfma(att2[2], w2, acc);
                rv[e] = hv[i][e] + acc.x + acc.y;
            }
            ln6(rv, g1, c1, hv[i]);

            // FF: 18 hidden units (packed over d), relu, pack pairs, then
            // contraction back over ff pairs (stride-1 in W2 rows).
            f32x2 h2[3];
            h2[0].x = hv[i][0]; h2[0].y = hv[i][1];
            h2[1].x = hv[i][2]; h2[1].y = hv[i][3];
            h2[2].x = hv[i][4]; h2[2].y = hv[i][5];
            f32x2 fp[9];
#pragma unroll
            for (int ff = 0; ff < FFD; ++ff) {
                const float* wr = W1 + ff*6;
                f32x2 w0; w0.x = wr[0]; w0.y = wr[1];
                f32x2 w1; w1.x = wr[2]; w1.y = wr[3];
                f32x2 w2; w2.x = wr[4]; w2.y = wr[5];
                f32x2 acc; acc.x = bb1[ff]; acc.y = 0.f;
                acc = pkfma(h2[0], w0, acc);
                acc = pkfma(h2[1], w1, acc);
                acc = pkfma(h2[2], w2, acc);
                float a = fmaxf(acc.x + acc.y, 0.f);
                if (ff & 1) fp[ff >> 1].y = a; else fp[ff >> 1].x = a;
            }
            float rv2[6];
#pragma unroll
            for (int d = 0; d < 6; ++d) {
                const f32x2* w2r = (const f32x2*)(W2 + d*FFD);
                f32x2 acc; acc.x = bb2[d]; acc.y = 0.f;
#pragma unroll
                for (int j = 0; j < 9; ++j)
                    acc = pkfma(fp[j], w2r[j], acc);
                rv2[d] = hv[i][d] + acc.x + acc.y;
            }
            ln6(rv2, g2, c2, hv[i]);
        }
    }

    // ---- final residual+relu (registers), head GEMV (r3-verbatim) ----
    float hf[3][6];
#pragma unroll
    for (int i = 0; i < 3; ++i) {
        int r = L + 64*i;
        bool real = (r < LAG);
#pragma unroll
        for (int d = 0; d < 6; ++d)
            hf[i][d] = real ? fmaxf(hv[i][d] + xv[i][d], 0.f) : 0.f;
    }
    float pt[24];
#pragma unroll
    for (int t = 0; t < 24; ++t) pt[t] = 0.f;
#pragma unroll
    for (int i = 0; i < 3; ++i) {
        int r = L + 64*i;
        if (r < LAG) {
            const float* wr = hw + r*6;
#pragma unroll
            for (int t = 0; t < 24; ++t) {
                const float2* wp = (const float2*)(wr + t*1008);
                float2 w0 = wp[0], w1 = wp[1], w2 = wp[2];
                pt[t] += w0.x*hf[i][0] + w0.y*hf[i][1] + w1.x*hf[i][2]
                       + w1.y*hf[i][3] + w2.x*hf[i][4] + w2.y*hf[i][5];
            }
        }
    }
#pragma unroll
    for (int t = 0; t < 24; ++t) lds[HEADS + L*25 + t] = pt[t];
    if (L < HOR) {
        float s = hb[L];
#pragma unroll 8
        for (int j = 0; j < 64; ++j) s += lds[HEADS + j*25 + L];
        out[(size_t)b*HOR + L] = s;
    }
}

extern "C" void kernel_launch(void* const* d_in, const int* in_sizes, int n_in,
                              void* d_out, int out_size, void* d_ws, size_t ws_size,
                              hipStream_t stream) {
    const float* input   = (const float*)d_in[0];
    const float* pos_emb = (const float*)d_in[1];
    const float* ipw     = (const float*)d_in[2];
    const float* ipb     = (const float*)d_in[3];
    const float* ow      = (const float*)d_in[4];
    const float* ob      = (const float*)d_in[5];
    const float* l1g     = (const float*)d_in[6];
    const float* l1b     = (const float*)d_in[7];
    const float* f1w     = (const float*)d_in[8];
    const float* f1b     = (const float*)d_in[9];
    const float* f2w     = (const float*)d_in[10];
    const float* f2b     = (const float*)d_in[11];
    const float* l2g     = (const float*)d_in[12];
    const float* l2b     = (const float*)d_in[13];
    const float* hw      = (const float*)d_in[14];
    const float* hb      = (const float*)d_in[15];
    float* out = (float*)d_out;

    const int B = in_sizes[0] / LAG;
    tfenc_kernel<<<dim3(B), dim3(64), 0, stream>>>(
        input, pos_emb, ipw, ipb, ow, ob, l1g, l1b,
        f1w, f1b, f2w, f2b, l2g, l2b, hw, hb, out);
}